// Round 9
// baseline (468.111 us; speedup 1.0000x reference)
//
#include <hip/hip_runtime.h>
#include <hip/hip_bf16.h>

typedef __bf16 bf16x8_t __attribute__((ext_vector_type(8)));
typedef float  f32x4_t  __attribute__((ext_vector_type(4)));

#define B_     2
#define L_     2048
#define D_     2048
#define H_     16
#define DH_    128
#define INNER_ 2048
#define M_     (B_ * L_)

// async global->LDS, 16B per lane. LDS dest must be wave-uniform base + lane*16.
__device__ __forceinline__ void gld_lds16(const void* g, void* l) {
    __builtin_amdgcn_global_load_lds(
        (const __attribute__((address_space(1))) void*)g,
        (__attribute__((address_space(3))) void*)l,
        16, 0, 0);
}

__device__ __forceinline__ unsigned short f2bf(float f) {
    __hip_bfloat16 h = __float2bfloat16(f);
    return *(unsigned short*)&h;
}
__device__ __forceinline__ float bf2f(unsigned short s) {
    return __uint_as_float(((unsigned)s) << 16);
}

// ---------------------------------------------------------------- fused prep:
// z = 0..3 -> weight transpose+cast (wq,wk,wv,wo); z = 4 -> cast x (bf16).
__global__ __launch_bounds__(256)
void k_prep(const float* __restrict__ x,
            const float* __restrict__ w0, const float* __restrict__ w1,
            const float* __restrict__ w2, const float* __restrict__ w3,
            unsigned short* __restrict__ xb,
            unsigned short* __restrict__ d0, unsigned short* __restrict__ d1,
            unsigned short* __restrict__ d2, unsigned short* __restrict__ d3) {
    const int z = blockIdx.z;
    const int t = threadIdx.x;
    if (z == 4) {
        const size_t base = ((size_t)(blockIdx.y * 64 + blockIdx.x) * 256 + t) * 8;
        float4 v0 = *(const float4*)(x + base);
        float4 v1 = *(const float4*)(x + base + 4);
        ushort4 o0, o1;
        o0.x = f2bf(v0.x); o0.y = f2bf(v0.y); o0.z = f2bf(v0.z); o0.w = f2bf(v0.w);
        o1.x = f2bf(v1.x); o1.y = f2bf(v1.y); o1.z = f2bf(v1.z); o1.w = f2bf(v1.w);
        *(ushort4*)(xb + base)     = o0;
        *(ushort4*)(xb + base + 4) = o1;
        return;
    }
    const float* in = (z == 0) ? w0 : (z == 1) ? w1 : (z == 2) ? w2 : w3;
    unsigned short* out = (z == 0) ? d0 : (z == 1) ? d1 : (z == 2) ? d2 : d3;
    __shared__ unsigned short tile[32][33];
    const int r  = t >> 3;
    const int c4 = (t & 7) << 2;
    const size_t ib = ((size_t)blockIdx.y * 32 + r) * 2048 + blockIdx.x * 32 + c4;
    float4 v = *(const float4*)(in + ib);
    tile[r][c4 + 0] = f2bf(v.x); tile[r][c4 + 1] = f2bf(v.y);
    tile[r][c4 + 2] = f2bf(v.z); tile[r][c4 + 3] = f2bf(v.w);
    __syncthreads();
    ushort4 o;
    o.x = tile[c4 + 0][r]; o.y = tile[c4 + 1][r];
    o.z = tile[c4 + 2][r]; o.w = tile[c4 + 3][r];
    const size_t ob = ((size_t)blockIdx.x * 32 + r) * 2048 + blockIdx.y * 32 + c4;
    *(ushort4*)(out + ob) = o;
}

// ---------------------------------------------------------------- shared pipeline macros
#define FENCE asm volatile("" ::: "memory")
#define BAR   do { FENCE; __builtin_amdgcn_s_barrier(); FENCE; } while (0)
#define WVM19 asm volatile("s_waitcnt vmcnt(19)" ::: "memory")
#define WVM11 asm volatile("s_waitcnt vmcnt(11)" ::: "memory")
#define WVM4  asm volatile("s_waitcnt vmcnt(4)" ::: "memory")
#define WVM2  asm volatile("s_waitcnt vmcnt(2)" ::: "memory")
#define WVM0  asm volatile("s_waitcnt vmcnt(0)" ::: "memory")

// ---------------------------------------------------------------- fused QKV GEMM
// Round-9: A-operand DIRECT FROM GLOBAL (fragment layout == row-major layout:
// lane l16 = row, quad = 8 contiguous k). Removes A from the LDS port:
// ds_reads 20->12 per wave per K-tile, staging DMA 56->24 KB -> LDS port
// ~960 cy << MFMA 1862 cy. B stays LDS (triple-buffered, chunk-swizzled).
// vm FIFO: 11 ops/iter (3 B-DMA then 8 A-loads); end-of-iter vmcnt(19)
// retires exactly B(t+1) (19 = 8 A-loads of its iter + 11 of current) while
// B(t+2) and A(t+1) stay in flight. A(t+1) loaded during tile t (ping-pong
// afA/afB via 2x-unrolled loop, all register indices static). LDS 72 KiB.
#define QSTG_B(bbufe, u, kt)                                                    \
    gld_lds16(bS + ((size_t)(u) * 64) * D_ + (kt) * 64,                         \
              &lds[(bbufe) + (u) * 4096 + t * 8])
#define QLOADA(dst, kt) do {                                                    \
    _Pragma("unroll") for (int mi = 0; mi < 2; mi++)                            \
    _Pragma("unroll") for (int kk = 0; kk < 2; kk++)                            \
    _Pragma("unroll") for (int i = 0; i < 2; i++)                               \
        dst[mi][kk][i] = *(const bf16x8_t*)(aF +                                \
            (size_t)(mi * 32 + i * 16) * D_ + (kt) * 64 + kk * 32);             \
} while (0)
#define QBODY(afc, afn, it) do {                                                \
    const int rb = rbm * 12288;                                                 \
    const int sb = sbm * 12288;                                                 \
    const bool stA_ = (it) + 1 < 32;                                            \
    const bool stB_ = (it) + 2 < 32;                                            \
    if (stB_) { QSTG_B(sb, 0, (it) + 2); QSTG_B(sb, 1, (it) + 2);               \
                QSTG_B(sb, 2, (it) + 2); }                                      \
    if (stA_) { QLOADA(afn, (it) + 1); }                                        \
    _Pragma("unroll") for (int kk = 0; kk < 2; kk++) {                          \
        bf16x8_t bfr[6];                                                        \
        _Pragma("unroll") for (int jj = 0; jj < 6; jj++)                        \
            bfr[jj] = *(const bf16x8_t*)&lds[rb +                               \
                (wn + jj * 16 + l16) * 64 + (kk ? sw1 : sw0)];                  \
        __builtin_amdgcn_s_setprio(1);                                          \
        _Pragma("unroll") for (int mi = 0; mi < 2; mi++)                        \
        _Pragma("unroll") for (int i = 0; i < 2; i++)                           \
        _Pragma("unroll") for (int jj = 0; jj < 6; jj++)                        \
            acc[mi * 2 + i][jj] = __builtin_amdgcn_mfma_f32_16x16x32_bf16(      \
                afc[mi][kk][i], bfr[jj], acc[mi * 2 + i][jj], 0, 0, 0);         \
        __builtin_amdgcn_s_setprio(0);                                          \
    }                                                                           \
    if (stB_) { WVM19; } else { WVM0; }                                         \
    BAR;                                                                        \
    rbm = (rbm == 2) ? 0 : rbm + 1;                                             \
    sbm = (sbm == 2) ? 0 : sbm + 1;                                             \
} while (0)

__global__ __launch_bounds__(512, 2)
void k_gemm_qkv(const __hip_bfloat16* __restrict__ A,
                const __hip_bfloat16* __restrict__ Bt,
                const float* __restrict__ bq, const float* __restrict__ bk,
                const float* __restrict__ bv,
                __hip_bfloat16* __restrict__ qo, __hip_bfloat16* __restrict__ ko,
                __hip_bfloat16* __restrict__ vTo) {
    __shared__ __align__(16) __hip_bfloat16 lds[36864];  // 72 KiB (B only, 3 bufs)

    const int wg   = blockIdx.x;
    const int xcd  = wg & 7;
    const int loc  = wg >> 3;                  // 0..63
    const int bx   = ((xcd & 1) << 3) + (loc & 7);    // 16 M-tiles
    const int by   = ((xcd >> 1) << 3) + (loc >> 3);  // 32 N-tiles
    const int tileM = bx << 8;                 // BM=256
    const int tileN = by * 192;                // BN=192

    const int t    = threadIdx.x;
    const int lane = t & 63;
    const int wave = t >> 6;
    const int quad = lane >> 4;
    const int l16  = lane & 15;
    const int wm   = (wave >> 1) << 6;         // 0/64/128/192
    const int wn   = (wave & 1) * 96;          // 0/96

    const int sw0 = ((quad)     ^ (l16 & 7)) << 3;
    const int sw1 = ((quad + 4) ^ (l16 & 7)) << 3;

    // B stage-side (unchanged chunk swizzle)
    const int r8  = t >> 3;                    // 0..63
    const int qch = (t & 7) ^ (r8 & 7);
    const __hip_bfloat16* bS = Bt + (size_t)(tileN + r8) * D_ + qch * 8;
    // A fragment base: lane (l16, quad) reads row tileM+wm+..+l16, k quad*8+..
    const __hip_bfloat16* aF = A + (size_t)(tileM + wm + l16) * D_ + quad * 8;

    f32x4_t acc[4][6];
#pragma unroll
    for (int i = 0; i < 4; i++)
#pragma unroll
        for (int j = 0; j < 6; j++) acc[i][j] = (f32x4_t){0.f, 0.f, 0.f, 0.f};
    bf16x8_t afA[2][2][2], afB[2][2][2];

    // prologue: B(0)->buf0, B(1)->buf1, A(0)->afA; retire B(0) (11 newer ops)
    QSTG_B(0, 0, 0);     QSTG_B(0, 1, 0);     QSTG_B(0, 2, 0);
    QSTG_B(12288, 0, 1); QSTG_B(12288, 1, 1); QSTG_B(12288, 2, 1);
    QLOADA(afA, 0);
    WVM11;
    BAR;

    int rbm = 0;
    int sbm = 2;
#pragma unroll 1
    for (int it2 = 0; it2 < 16; ++it2) {
        QBODY(afA, afB, 2 * it2);
        QBODY(afB, afA, 2 * it2 + 1);
    }

    // epilogue: section boundaries (2048,4096) are 16-aligned -> sel is
    // fragment-uniform even though 192 does not divide 2048.
#pragma unroll
    for (int ai = 0; ai < 4; ai++) {
        const int m = tileM + wm + ai * 16 + quad * 4;
#pragma unroll
        for (int bj = 0; bj < 6; bj++) {
            const int n0  = tileN + wn + bj * 16;
            const int sel = n0 >> 11;            // 0=q, 1=k, 2=v
            const int n   = (n0 & (INNER_ - 1)) + l16;
            if (sel < 2) {
                const float* bias = sel ? bk : bq;
                __hip_bfloat16* C = sel ? ko : qo;
                const float bn = bias[n];
#pragma unroll
                for (int r = 0; r < 4; r++)
                    C[(size_t)(m + r) * INNER_ + n] =
                        __float2bfloat16(acc[ai][bj][r] + bn);
            } else {
                const int hh = n >> 7, dd = n & 127;
                const int bb = tileM >> 11;
                const int l0 = m & (L_ - 1);
                const float bvn = bv[n];
                ushort4 pk;
                pk.x = f2bf(acc[ai][bj][0] + bvn);
                pk.y = f2bf(acc[ai][bj][1] + bvn);
                pk.z = f2bf(acc[ai][bj][2] + bvn);
                pk.w = f2bf(acc[ai][bj][3] + bvn);
                *(ushort4*)(vTo + ((size_t)(bb * H_ + hh) * DH_ + dd) * L_ + l0) = pk;
            }
        }
    }
}

// ---------------------------------------------------------------- wo GEMM
// 256x128 pipelined (unchanged).
#define WAB0 0
#define WAB1 16384
#define WBB0 32768

#define WSTG_A(abufe, u, kt)                                                    \
    gld_lds16(aS + ((size_t)(u) * 64) * INNER_ + (kt) * 64,                     \
              &lds[(abufe) + (u) * 4096 + t * 8])
#define WSTG_B(bbufe, u, kt)                                                    \
    gld_lds16(bS + ((size_t)(u) * 64) * INNER_ + (kt) * 64,                     \
              &lds[(bbufe) + (u) * 4096 + t * 8])
#define WDSA(abufe) do {                                                        \
    _Pragma("unroll") for (int kk = 0; kk < 2; kk++)                            \
    _Pragma("unroll") for (int i = 0; i < 4; i++)                               \
        af[kk][i] = *(const bf16x8_t*)&lds[(abufe) +                            \
            (wm + i * 16 + l16) * 64 + (kk ? sw1 : sw0)];                       \
} while (0)
#define WDSB(bbufe) do {                                                        \
    _Pragma("unroll") for (int kk = 0; kk < 2; kk++)                            \
    _Pragma("unroll") for (int jj = 0; jj < 4; jj++)                            \
        bfr[kk][jj] = *(const bf16x8_t*)&lds[(bbufe) +                          \
            (wn + jj * 16 + l16) * 64 + (kk ? sw1 : sw0)];                      \
} while (0)
#define WMM do {                                                                \
    __builtin_amdgcn_s_setprio(1);                                              \
    _Pragma("unroll") for (int kk = 0; kk < 2; kk++)                            \
    _Pragma("unroll") for (int i = 0; i < 4; i++)                               \
    _Pragma("unroll") for (int jj = 0; jj < 4; jj++)                            \
        acc[i][jj] = __builtin_amdgcn_mfma_f32_16x16x32_bf16(                   \
            af[kk][i], bfr[kk][jj], acc[i][jj], 0, 0, 0);                       \
    __builtin_amdgcn_s_setprio(0);                                              \
} while (0)

__global__ __launch_bounds__(512, 2)
void k_gemm_wo(const __hip_bfloat16* __restrict__ A,
               const __hip_bfloat16* __restrict__ Bt,
               const float* __restrict__ bias,
               float* __restrict__ C) {
    __shared__ __align__(16) __hip_bfloat16 lds[57344];  // 112 KiB

    const int wg   = blockIdx.x;
    const int xcd  = wg & 7;
    const int loc  = wg >> 3;                  // 0..31
    const int bx   = ((xcd & 1) << 3) + (loc & 7);    // 16 M-tiles
    const int by   = ((xcd >> 1) << 2) + (loc >> 3);  // 16 N-tiles
    const int tileM = bx << 8;                 // BM=256
    const int tileN = by << 7;                 // BN=128

    const int t    = threadIdx.x;
    const int lane = t & 63;
    const int wave = t >> 6;
    const int quad = lane >> 4;
    const int l16  = lane & 15;
    const int wm   = (wave >> 1) << 6;         // 0/64/128/192
    const int wn   = (wave & 1) << 6;          // 0/64

    const int sw0 = ((quad)     ^ (l16 & 7)) << 3;
    const int sw1 = ((quad + 4) ^ (l16 & 7)) << 3;

    const int r8  = t >> 3;                    // 0..63
    const int qch = (t & 7) ^ (r8 & 7);
    const __hip_bfloat16* aS = A  + (size_t)(tileM + r8) * INNER_ + qch * 8;
    const __hip_bfloat16* bS = Bt + (size_t)(tileN + r8) * INNER_ + qch * 8;

    WSTG_A(WAB0, 0, 0); WSTG_A(WAB0, 1, 0); WSTG_A(WAB0, 2, 0); WSTG_A(WAB0, 3, 0);
    WSTG_B(WBB0, 0, 0); WSTG_B(WBB0, 1, 0);
    WSTG_B(WBB0 + 8192, 0, 1); WSTG_B(WBB0 + 8192, 1, 1);
    WVM2;
    BAR;

    f32x4_t acc[4][4];
#pragma unroll
    for (int i = 0; i < 4; i++)
#pragma unroll
        for (int j = 0; j < 4; j++) acc[i][j] = (f32x4_t){0.f, 0.f, 0.f, 0.f};
    bf16x8_t af[2][4], bfr[2][4];

    int rbm = 0;
    int sbm = 2;
#pragma unroll 1
    for (int it = 0; it < 32; ++it) {
        const int ra = (it & 1) ? WAB1 : WAB0;
        const int sa = (it & 1) ? WAB0 : WAB1;
        const int rb = WBB0 + rbm * 8192;
        const int sb = WBB0 + sbm * 8192;
        const bool stA = (it + 1 < 32);
        const bool stB = (it + 2 < 32);

        if (stA) { WSTG_A(sa, 0, it + 1); WSTG_A(sa, 1, it + 1);
                   WSTG_A(sa, 2, it + 1); WSTG_A(sa, 3, it + 1); }
        if (stB) { WSTG_B(sb, 0, it + 2); WSTG_B(sb, 1, it + 2); }

        WDSA(ra);
        WDSB(rb);
        WMM;

        if (stB) { WVM2; } else if (stA) { WVM0; }
        BAR;

        rbm = (rbm == 2) ? 0 : rbm + 1;
        sbm = (sbm == 2) ? 0 : sbm + 1;
    }

#pragma unroll
    for (int i = 0; i < 4; i++) {
        const int m = tileM + wm + i * 16 + quad * 4;
#pragma unroll
        for (int j = 0; j < 4; j++) {
            const int n = tileN + wn + j * 16 + l16;
            const float bn = bias[n];
#pragma unroll
            for (int r = 0; r < 4; r++)
                C[(size_t)(m + r) * D_ + n] = acc[i][j][r] + bn;
        }
    }
}

// ---------------------------------------------------------------- RMSNorm + RoPE
// Fused q+k per row: 512 threads, threads 0-255 -> q, 256-511 -> k.
__global__ __launch_bounds__(512)
void k_rmsrope2(__hip_bfloat16* __restrict__ qb, __hip_bfloat16* __restrict__ kb,
                const float* __restrict__ qn, const float* __restrict__ kn,
                const float* __restrict__ pcos, const float* __restrict__ psin,
                const float* __restrict__ lls, float qextra) {
    const int row  = blockIdx.x;
    const int l    = row & (L_ - 1);
    const int t    = threadIdx.x;
    const int half = t >> 8;                 // 0 = q, 1 = k
    const int tt   = t & 255;
    __hip_bfloat16* buf = half ? kb : qb;
    const float* w = half ? kn : qn;
    __hip_bfloat16* p = buf + (size_t)row * INNER_ + tt * 8;

    float x[8];
    {
        const unsigned short* ps = (const unsigned short*)p;
        ushort4 a = *(const ushort4*)ps;
        ushort4 b = *(const ushort4*)(ps + 4);
        unsigned short s[8] = {a.x, a.y, a.z, a.w, b.x, b.y, b.z, b.w};
#pragma unroll
        for (int i = 0; i < 8; i++) x[i] = bf2f(s[i]);
    }
    float ss = 0.f;
#pragma unroll
    for (int i = 0; i < 8; i++) ss += x[i] * x[i];
#pragma unroll
    for (int off = 32; off >= 1; off >>= 1) ss += __shfl_down(ss, off);
    __shared__ float red[8];
    if ((t & 63) == 0) red[t >> 6] = ss;
    __syncthreads();
    ss = half ? (red[4] + red[5]) + (red[6] + red[7])
              : (red[0] + red[1]) + (red[2] + red[3]);
    const float rstd = rsqrtf(ss * (1.0f / (float)INNER_) + 1e-6f);

    const float scale = half ? 1.0f : (qextra * lls[l]);

    const float4 c4 = ((const float4*)(pcos + (size_t)l * (INNER_ / 2)))[tt];
    const float4 s4 = ((const float4*)(psin + (size_t)l * (INNER_ / 2)))[tt];
    const float cc[4] = {c4.x, c4.y, c4.z, c4.w};
    const float sn[4] = {s4.x, s4.y, s4.z, s4.w};
    const float4 w0 = ((const float4*)w)[tt * 2];
    const float4 w1 = ((const float4*)w)[tt * 2 + 1];
    const float ww[8] = {w0.x, w0.y, w0.z, w0.w, w1.x, w1.y, w1.z, w1.w};

    union { __hip_bfloat16 h[8]; uint4 u; } pk;
#pragma unroll
    for (int pi = 0; pi < 4; pi++) {
        const float y1 = x[pi * 2]     * rstd * ww[pi * 2];
        const float y2 = x[pi * 2 + 1] * rstd * ww[pi * 2 + 1];
        pk.h[pi * 2]     = __float2bfloat16((y1 * cc[pi] - y2 * sn[pi]) * scale);
        pk.h[pi * 2 + 1] = __float2bfloat16((y1 * sn[pi] + y2 * cc[pi]) * scale);
    }
    *(uint4*)p = pk.u;
}

// ---------------------------------------------------------------- attention
// R6 version (best measured): QBLK=128, 8 waves, K/V double-buffered staging,
// raw barriers + counted vmcnt(4); q-tile pairing (p, 15-p).
__global__ __launch_bounds__(512)
void k_attn(const __hip_bfloat16* __restrict__ q,
            const __hip_bfloat16* __restrict__ k,
            const __hip_bfloat16* __restrict__ vT,
            __hip_bfloat16* __restrict__ o) {
    __shared__ __align__(16) __hip_bfloat16 Ks[2][64 * 128];   // [key][d] swizzled
    __shared__ __align__(16) __hip_bfloat16 Vs[2][128 * 64];   // [d][key] swizzled
    __shared__ __align__(16) __hip_bfloat16 Pt[8][16 * 72];    // [wave][qrow][key]

    const int p  = blockIdx.x;   // 0..7
    const int bh = blockIdx.y;
    const int b  = bh >> 4;
    const int h  = bh & 15;
    const int t = threadIdx.x, wave = t >> 6, lane = t & 63;
    const int quad = lane >> 4, l16 = lane & 15;

    const int kr = t >> 4;                          // 0..31
    const int kc = ((t & 15) ^ (kr & 15)) << 3;
    const int vr = t >> 3;                          // 0..63
    const int vc = ((t & 7) ^ (vr & 7)) << 3;
    const __hip_bfloat16* kbase = k  + (size_t)b * L_ * INNER_ + h * DH_;
    const __hip_bfloat16* vbase = vT + (size_t)bh * DH_ * L_;

#define STGKV(kt_, b_) do {                                                      \
    const int kv0_ = (kt_) * 64;                                                 \
    gld_lds16(kbase + (size_t)(kv0_ + kr)      * INNER_ + kc, &Ks[b_][t * 8]);   \
    gld_lds16(kbase + (size_t)(kv0_ + 32 + kr) * INNER_ + kc, &Ks[b_][4096 + t * 8]); \
    gld_lds16(vbase + (size_t)vr        * L_ + kv0_ + vc, &Vs[b_][t * 8]);       \
    gld_lds16(vbase + (size_t)(64 + vr) * L_ + kv0_ + vc, &Vs[b_][4096 + t * 8]);\
} while (0)

    for (int half = 0; half < 2; ++half) {
        const int qt = half ? (15 - p) : p;
        const int rowbase = qt * 128 + wave * 16;

        bf16x8_t aq[4];
        {
            const size_t qoff = (size_t)(b * L_ + rowbase + l16) * INNER_ + h * DH_;
#pragma unroll
            for (int kk = 0; kk < 4; kk++)
                aq[kk] = *(const bf16x8_t*)(q + qoff + kk * 32 + quad * 8);
        }

        f32x4_t oacc[8];
#pragma unroll
        for (int jj = 0; jj < 8; jj++) oacc[jj] = (f32x4_t){0.f, 0.f, 0.f, 0.f};
        float m_ = -1e30f, l_ = 0.f;

        const int nkt = 2 * qt + 2;
        STGKV(0, 0);                              // prologue
#pragma unroll 1
        for (int kt = 0; kt < nkt; ++kt) {
            const int kv0 = kt * 64;
            const int cur = kt & 1;
            const bool more = (kt + 1 < nkt);
            if (more) STGKV(kt + 1, cur ^ 1);     // prefetch next tile
            if (more) { WVM4; } else { WVM0; }    // current tile's 4 loads done
            BAR;

            if (kv0 <= rowbase + 15) {
                f32x4_t sacc[4];
#pragma unroll
                for (int tt = 0; tt < 4; tt++) sacc[tt] = (f32x4_t){0.f, 0.f, 0.f, 0.f};
#pragma unroll
                for (int kk = 0; kk < 4; kk++) {
                    bf16x8_t kf[4];
#pragma unroll
                    for (int tt = 0; tt < 4; tt++)
                        kf[tt] = *(const bf16x8_t*)&Ks[cur][(tt * 16 + l16) * 128 + (((kk * 4 + quad) ^ l16) << 3)];
#pragma unroll
                    for (int tt = 0; tt < 4; tt++)
                        sacc[tt] = __builtin_amdgcn_mfma_f32_16x16x32_bf16(
                            kf[tt], aq[kk], sacc[tt], 0, 0, 0);
                }

                if (kv0 + 63 > rowbase) {
                    const int qrow = rowbase + l16;
#pragma unroll
                    for (int tt = 0; tt < 4; tt++)
#pragma unroll
                        for (int r = 0; r < 4; r++)
                            if (kv0 + tt * 16 + quad * 4 + r > qrow) sacc[tt][r] = -1e30f;
                }

                float mx = sacc[0][0];
#pragma unroll
                for (int tt = 0; tt < 4; tt++)
#pragma unroll
                    for (int r = 0; r < 4; r++) mx = fmaxf(mx, sacc[tt][r]);
                mx = fmaxf(mx, __shfl_xor(mx, 16));
                mx = fmaxf(mx, __shfl_xor(mx, 32));
                const float mnew = fmaxf(m_, mx);
                const float alpha = exp2f(m_ - mnew);
                m_ = mnew;

                float ls = 0.f;
#pragma unroll
                for (int tt = 0; tt < 4; tt++) {
                    ushort4 pk;
                    float p0 = exp2f(sacc[tt][0] - mnew);
                    float p1 = exp2f(sacc[tt][1] - mnew);
                    float p2 = exp2f(sacc[tt][2] - mnew);
                    float p3 = exp2f(sacc[tt][3] - mnew);
                    ls += (p0 + p1) + (p2 + p3);
                    pk.x = f2bf(p0); pk.y = f2bf(p1); pk.z = f2bf(p2); pk.w = f2bf(p3);
                    *(ushort4*)&Pt[wave][l16 * 72 + tt * 16 + quad * 4] = pk;
                }
                ls += __shfl_xor(ls, 16);
                ls += __shfl_xor(ls, 32);
                l_ = l_ * alpha + ls;
#pragma unroll
                for (int jj = 0; jj < 8; jj++) {
                    oacc[jj][0] *= alpha; oacc[jj][1] *= alpha;
                    oacc[jj][2] *= alpha; oacc[jj][3] *= alpha;
                }

#pragma unroll
                for (int kk2 = 0; kk2 < 2; kk2++) {
                    bf16x8_t pf = *(const bf16x8_t*)&Pt[wave][l16 * 72 + kk2 * 32 + quad * 8];
#pragma unroll
                    for (int jj = 0; jj < 8; jj++) {
                        bf16x8_t vf = *(const bf16x8_t*)
                            &Vs[cur][(jj * 16 + l16) * 64 + (((kk2 * 4 + quad) ^ (l16 & 7)) << 3)];
                        oacc[jj] = __builtin_amdgcn_mfma_f32_16x16x32_bf16(vf, pf, oacc[jj], 0, 0, 0);
                    }
                }
            }
            BAR;
        }

        {
            const float inv = 1.0f / l_;
            __hip_bfloat16* orow = o + (size_t)(b * L_ + rowbase + l16) * INNER_ + h * DH_;
#pragma unroll
            for (int jj = 0; jj < 8; jj++) {
                ushort4 pk;
                pk.x = f2bf(oacc[jj][0] * inv);
                pk.y = f2bf(oacc[jj][1] * inv);
                pk.z = f2bf(oacc[jj][2] * inv);
                pk.w = f2bf(oacc[jj][3] * inv);
                *(ushort4*)(orow + jj * 16 + quad * 4) = pk;
            }
        }
    }
#undef STGKV
}

// ---------------------------------------------------------------- launch
extern "C" void kernel_launch(void* const* d_in, const int* in_sizes, int n_in,
                              void* d_out, int out_size, void* d_ws, size_t ws_size,
                              hipStream_t stream) {
    const float* x      = (const float*)d_in[0];
    const float* pe_cos = (const float*)d_in[1];
    const float* pe_sin = (const float*)d_in[2];
    const float* lls    = (const float*)d_in[3];
    const float* wq     = (const float*)d_in[4];
    const float* bq     = (const float*)d_in[5];
    const float* wk     = (const float*)d_in[6];
    const float* bk     = (const float*)d_in[7];
    const float* wv     = (const float*)d_in[8];
    const float* bv     = (const float*)d_in[9];
    const float* qn     = (const float*)d_in[10];
    const float* kn     = (const float*)d_in[11];
    const float* wo     = (const float*)d_in[12];
    const float* bo     = (const float*)d_in[13];

    char* ws = (char*)d_ws;
    const size_t SZ_W = (size_t)D_ * INNER_ * 2;   // 8 MB (bf16)
    const size_t SZ_M = (size_t)M_ * INNER_ * 2;   // 16 MB (bf16)
    __hip_bfloat16* xb     = (__hip_bfloat16*)ws;  ws += SZ_M;
    __hip_bfloat16* wqkvT  = (__hip_bfloat16*)ws;  ws += 3 * SZ_W;  // [6144][2048]
    __hip_bfloat16* woT    = (__hip_bfloat16*)ws;  ws += SZ_W;
    __hip_bfloat16* qb     = (__hip_bfloat16*)ws;  ws += SZ_M;
    __hip_bfloat16* kb     = (__hip_bfloat16*)ws;  ws += SZ_M;
    __hip_bfloat16* vT     = (__hip_bfloat16*)ws;  ws += SZ_M;
    __hip_bfloat16* ab     = (__hip_bfloat16*)ws;  ws += SZ_M;
    (void)in_sizes; (void)n_in; (void)out_size; (void)ws_size;

    // 0+1. fused: cast x (z=4) + all 4 weight transpose+casts (z=0..3)
    k_prep<<<dim3(64, 64, 5), dim3(256), 0, stream>>>(
        x, wq, wk, wv, wo,
        (unsigned short*)xb,
        (unsigned short*)wqkvT,
        (unsigned short*)(wqkvT + (size_t)INNER_ * D_),
        (unsigned short*)(wqkvT + 2 * (size_t)INNER_ * D_),
        (unsigned short*)woT);

    // 2. fused QKV projection: A direct-from-global, B via LDS
    k_gemm_qkv<<<dim3(512), dim3(512), 0, stream>>>(xb, wqkvT, bq, bk, bv, qb, kb, vT);

    // 3. RMSNorm + RoPE, q+k fused per row
    const float qextra = 0.08838834764831843f /* rsqrt(128) */ * 1.4426950408889634f /* log2 e */;
    k_rmsrope2<<<dim3(M_), dim3(512), 0, stream>>>(qb, kb, qn, kn, pe_cos, pe_sin, lls, qextra);

    // 4. causal flash attention (R6 best: QBLK=128, dbuf K/V)
    k_attn<<<dim3(8, B_ * H_), dim3(512), 0, stream>>>(qb, kb, vT, ab);

    // 5. output projection -> d_out (f32)
    k_gemm_wo<<<dim3(256), dim3(512), 0, stream>>>(ab, woT, bo, (float*)d_out);
}

// Round 11
// 402.220 us; speedup vs baseline: 1.1638x; 1.1638x over previous
//
#include <hip/hip_runtime.h>
#include <hip/hip_bf16.h>

typedef __bf16 bf16x8_t __attribute__((ext_vector_type(8)));
typedef float  f32x4_t  __attribute__((ext_vector_type(4)));

#define B_     2
#define L_     2048
#define D_     2048
#define H_     16
#define DH_    128
#define INNER_ 2048
#define M_     (B_ * L_)

// async global->LDS, 16B per lane. LDS dest must be wave-uniform base + lane*16.
__device__ __forceinline__ void gld_lds16(const void* g, void* l) {
    __builtin_amdgcn_global_load_lds(
        (const __attribute__((address_space(1))) void*)g,
        (__attribute__((address_space(3))) void*)l,
        16, 0, 0);
}

__device__ __forceinline__ unsigned short f2bf(float f) {
    __hip_bfloat16 h = __float2bfloat16(f);
    return *(unsigned short*)&h;
}
__device__ __forceinline__ float bf2f(unsigned short s) {
    return __uint_as_float(((unsigned)s) << 16);
}

// ---------------------------------------------------------------- fused prep:
// z = 0..3 -> weight transpose+cast (wq,wk,wv,wo); z = 4 -> cast x (bf16).
__global__ __launch_bounds__(256)
void k_prep(const float* __restrict__ x,
            const float* __restrict__ w0, const float* __restrict__ w1,
            const float* __restrict__ w2, const float* __restrict__ w3,
            unsigned short* __restrict__ xb,
            unsigned short* __restrict__ d0, unsigned short* __restrict__ d1,
            unsigned short* __restrict__ d2, unsigned short* __restrict__ d3) {
    const int z = blockIdx.z;
    const int t = threadIdx.x;
    if (z == 4) {
        const size_t base = ((size_t)(blockIdx.y * 64 + blockIdx.x) * 256 + t) * 8;
        float4 v0 = *(const float4*)(x + base);
        float4 v1 = *(const float4*)(x + base + 4);
        ushort4 o0, o1;
        o0.x = f2bf(v0.x); o0.y = f2bf(v0.y); o0.z = f2bf(v0.z); o0.w = f2bf(v0.w);
        o1.x = f2bf(v1.x); o1.y = f2bf(v1.y); o1.z = f2bf(v1.z); o1.w = f2bf(v1.w);
        *(ushort4*)(xb + base)     = o0;
        *(ushort4*)(xb + base + 4) = o1;
        return;
    }
    const float* in = (z == 0) ? w0 : (z == 1) ? w1 : (z == 2) ? w2 : w3;
    unsigned short* out = (z == 0) ? d0 : (z == 1) ? d1 : (z == 2) ? d2 : d3;
    __shared__ unsigned short tile[32][33];
    const int r  = t >> 3;
    const int c4 = (t & 7) << 2;
    const size_t ib = ((size_t)blockIdx.y * 32 + r) * 2048 + blockIdx.x * 32 + c4;
    float4 v = *(const float4*)(in + ib);
    tile[r][c4 + 0] = f2bf(v.x); tile[r][c4 + 1] = f2bf(v.y);
    tile[r][c4 + 2] = f2bf(v.z); tile[r][c4 + 3] = f2bf(v.w);
    __syncthreads();
    ushort4 o;
    o.x = tile[c4 + 0][r]; o.y = tile[c4 + 1][r];
    o.z = tile[c4 + 2][r]; o.w = tile[c4 + 3][r];
    const size_t ob = ((size_t)blockIdx.x * 32 + r) * 2048 + blockIdx.y * 32 + c4;
    *(ushort4*)(out + ob) = o;
}

// ---------------------------------------------------------------- shared pipeline macros
#define FENCE asm volatile("" ::: "memory")
#define BAR   do { FENCE; __builtin_amdgcn_s_barrier(); FENCE; } while (0)
#define WVM4  asm volatile("s_waitcnt vmcnt(4)" ::: "memory")
#define WVM3  asm volatile("s_waitcnt vmcnt(3)" ::: "memory")
#define WVM2  asm volatile("s_waitcnt vmcnt(2)" ::: "memory")
#define WVM0  asm volatile("s_waitcnt vmcnt(0)" ::: "memory")

// ---------------------------------------------------------------- fused QKV GEMM
// 256x192 tile, BK=64, 512 blocks = 2 perfect rounds. (Best verified variant:
// VGPR 100, A dbuf + B triple-buf via LDS, single barrier + counted vmcnt(3)
// per K-tile, T2 chunk swizzle, XCD 8x8 regions.)
#define AB0 0
#define AB1 16384
#define BB0 32768

#define QSTG_A(abufe, u, kt)                                                    \
    gld_lds16(aS + ((size_t)(u) * 64) * D_ + (kt) * 64,                         \
              &lds[(abufe) + (u) * 4096 + t * 8])
#define QSTG_B(bbufe, u, kt)                                                    \
    gld_lds16(bS + ((size_t)(u) * 64) * D_ + (kt) * 64,                         \
              &lds[(bbufe) + (u) * 4096 + t * 8])
#define QDSA2(abufe) do {                                                       \
    _Pragma("unroll") for (int mi = 0; mi < 2; mi++)                            \
    _Pragma("unroll") for (int kk = 0; kk < 2; kk++)                            \
    _Pragma("unroll") for (int i = 0; i < 2; i++)                               \
        af[mi][kk][i] = *(const bf16x8_t*)&lds[(abufe) +                        \
            (wm + mi * 32 + i * 16 + l16) * 64 + (kk ? sw1 : sw0)];             \
} while (0)
#define QDSB(bbufe) do {                                                        \
    _Pragma("unroll") for (int kk = 0; kk < 2; kk++)                            \
    _Pragma("unroll") for (int jj = 0; jj < 6; jj++)                            \
        bfr[kk][jj] = *(const bf16x8_t*)&lds[(bbufe) +                          \
            (wn + jj * 16 + l16) * 64 + (kk ? sw1 : sw0)];                      \
} while (0)
#define MMALL2 do {                                                             \
    __builtin_amdgcn_s_setprio(1);                                              \
    _Pragma("unroll") for (int mi = 0; mi < 2; mi++)                            \
    _Pragma("unroll") for (int kk = 0; kk < 2; kk++)                            \
    _Pragma("unroll") for (int i = 0; i < 2; i++)                               \
    _Pragma("unroll") for (int jj = 0; jj < 6; jj++)                            \
        acc[mi * 2 + i][jj] = __builtin_amdgcn_mfma_f32_16x16x32_bf16(          \
            af[mi][kk][i], bfr[kk][jj], acc[mi * 2 + i][jj], 0, 0, 0);          \
    __builtin_amdgcn_s_setprio(0);                                              \
} while (0)

__global__ __launch_bounds__(512, 2)
void k_gemm_qkv(const __hip_bfloat16* __restrict__ A,
                const __hip_bfloat16* __restrict__ Bt,
                const float* __restrict__ bq, const float* __restrict__ bk,
                const float* __restrict__ bv,
                __hip_bfloat16* __restrict__ qo, __hip_bfloat16* __restrict__ ko,
                __hip_bfloat16* __restrict__ vTo) {
    __shared__ __align__(16) __hip_bfloat16 lds[69632];  // 136 KiB

    const int wg   = blockIdx.x;
    const int xcd  = wg & 7;
    const int loc  = wg >> 3;                  // 0..63
    const int bx   = ((xcd & 1) << 3) + (loc & 7);    // 16 M-tiles
    const int by   = ((xcd >> 1) << 3) + (loc >> 3);  // 32 N-tiles
    const int tileM = bx << 8;                 // BM=256
    const int tileN = by * 192;                // BN=192

    const int t    = threadIdx.x;
    const int lane = t & 63;
    const int wave = t >> 6;
    const int quad = lane >> 4;
    const int l16  = lane & 15;
    const int wm   = (wave >> 1) << 6;         // 0/64/128/192
    const int wn   = (wave & 1) * 96;          // 0/96

    const int sw0 = ((quad)     ^ (l16 & 7)) << 3;
    const int sw1 = ((quad + 4) ^ (l16 & 7)) << 3;

    const int r8  = t >> 3;                    // 0..63
    const int qch = (t & 7) ^ (r8 & 7);
    const __hip_bfloat16* aS = A  + (size_t)(tileM + r8) * D_ + qch * 8;
    const __hip_bfloat16* bS = Bt + (size_t)(tileN + r8) * D_ + qch * 8;

    QSTG_A(AB0, 0, 0); QSTG_A(AB0, 1, 0); QSTG_A(AB0, 2, 0); QSTG_A(AB0, 3, 0);
    QSTG_B(BB0, 0, 0); QSTG_B(BB0, 1, 0); QSTG_B(BB0, 2, 0);
    QSTG_B(BB0 + 12288, 0, 1); QSTG_B(BB0 + 12288, 1, 1); QSTG_B(BB0 + 12288, 2, 1);
    WVM3;
    BAR;

    f32x4_t acc[4][6];
#pragma unroll
    for (int i = 0; i < 4; i++)
#pragma unroll
        for (int j = 0; j < 6; j++) acc[i][j] = (f32x4_t){0.f, 0.f, 0.f, 0.f};
    bf16x8_t af[2][2][2], bfr[2][6];

    int rbm = 0;
    int sbm = 2;
#pragma unroll 1
    for (int it = 0; it < 32; ++it) {
        const int ra = (it & 1) ? AB1 : AB0;
        const int sa = (it & 1) ? AB0 : AB1;
        const int rb = BB0 + rbm * 12288;
        const int sb = BB0 + sbm * 12288;
        const bool stA = (it + 1 < 32);
        const bool stB = (it + 2 < 32);

        if (stA) { QSTG_A(sa, 0, it + 1); QSTG_A(sa, 1, it + 1);
                   QSTG_A(sa, 2, it + 1); QSTG_A(sa, 3, it + 1); }
        if (stB) { QSTG_B(sb, 0, it + 2); QSTG_B(sb, 1, it + 2);
                   QSTG_B(sb, 2, it + 2); }

        QDSA2(ra);
        QDSB(rb);
        MMALL2;

        if (stB) { WVM3; } else if (stA) { WVM0; }
        BAR;

        rbm = (rbm == 2) ? 0 : rbm + 1;
        sbm = (sbm == 2) ? 0 : sbm + 1;
    }

#pragma unroll
    for (int ai = 0; ai < 4; ai++) {
        const int m = tileM + wm + ai * 16 + quad * 4;
#pragma unroll
        for (int bj = 0; bj < 6; bj++) {
            const int n0  = tileN + wn + bj * 16;
            const int sel = n0 >> 11;            // 0=q, 1=k, 2=v
            const int n   = (n0 & (INNER_ - 1)) + l16;
            if (sel < 2) {
                const float* bias = sel ? bk : bq;
                __hip_bfloat16* C = sel ? ko : qo;
                const float bn = bias[n];
#pragma unroll
                for (int r = 0; r < 4; r++)
                    C[(size_t)(m + r) * INNER_ + n] =
                        __float2bfloat16(acc[ai][bj][r] + bn);
            } else {
                const int hh = n >> 7, dd = n & 127;
                const int bb = tileM >> 11;
                const int l0 = m & (L_ - 1);
                const float bvn = bv[n];
                ushort4 pk;
                pk.x = f2bf(acc[ai][bj][0] + bvn);
                pk.y = f2bf(acc[ai][bj][1] + bvn);
                pk.z = f2bf(acc[ai][bj][2] + bvn);
                pk.w = f2bf(acc[ai][bj][3] + bvn);
                *(ushort4*)(vTo + ((size_t)(bb * H_ + hh) * DH_ + dd) * L_ + l0) = pk;
            }
        }
    }
}

// ---------------------------------------------------------------- wo GEMM
// 256x128 pipelined (unchanged).
#define WAB0 0
#define WAB1 16384
#define WBB0 32768

#define WSTG_A(abufe, u, kt)                                                    \
    gld_lds16(aS + ((size_t)(u) * 64) * INNER_ + (kt) * 64,                     \
              &lds[(abufe) + (u) * 4096 + t * 8])
#define WSTG_B(bbufe, u, kt)                                                    \
    gld_lds16(bS + ((size_t)(u) * 64) * INNER_ + (kt) * 64,                     \
              &lds[(bbufe) + (u) * 4096 + t * 8])
#define WDSA(abufe) do {                                                        \
    _Pragma("unroll") for (int kk = 0; kk < 2; kk++)                            \
    _Pragma("unroll") for (int i = 0; i < 4; i++)                               \
        af[kk][i] = *(const bf16x8_t*)&lds[(abufe) +                            \
            (wm + i * 16 + l16) * 64 + (kk ? sw1 : sw0)];                       \
} while (0)
#define WDSB(bbufe) do {                                                        \
    _Pragma("unroll") for (int kk = 0; kk < 2; kk++)                            \
    _Pragma("unroll") for (int jj = 0; jj < 4; jj++)                            \
        bfr[kk][jj] = *(const bf16x8_t*)&lds[(bbufe) +                          \
            (wn + jj * 16 + l16) * 64 + (kk ? sw1 : sw0)];                      \
} while (0)
#define WMM do {                                                                \
    __builtin_amdgcn_s_setprio(1);                                              \
    _Pragma("unroll") for (int kk = 0; kk < 2; kk++)                            \
    _Pragma("unroll") for (int i = 0; i < 4; i++)                               \
    _Pragma("unroll") for (int jj = 0; jj < 4; jj++)                            \
        acc[i][jj] = __builtin_amdgcn_mfma_f32_16x16x32_bf16(                   \
            af[kk][i], bfr[kk][jj], acc[i][jj], 0, 0, 0);                       \
    __builtin_amdgcn_s_setprio(0);                                              \
} while (0)

__global__ __launch_bounds__(512, 2)
void k_gemm_wo(const __hip_bfloat16* __restrict__ A,
               const __hip_bfloat16* __restrict__ Bt,
               const float* __restrict__ bias,
               float* __restrict__ C) {
    __shared__ __align__(16) __hip_bfloat16 lds[57344];  // 112 KiB

    const int wg   = blockIdx.x;
    const int xcd  = wg & 7;
    const int loc  = wg >> 3;                  // 0..31
    const int bx   = ((xcd & 1) << 3) + (loc & 7);    // 16 M-tiles
    const int by   = ((xcd >> 1) << 2) + (loc >> 3);  // 16 N-tiles
    const int tileM = bx << 8;                 // BM=256
    const int tileN = by << 7;                 // BN=128

    const int t    = threadIdx.x;
    const int lane = t & 63;
    const int wave = t >> 6;
    const int quad = lane >> 4;
    const int l16  = lane & 15;
    const int wm   = (wave >> 1) << 6;         // 0/64/128/192
    const int wn   = (wave & 1) << 6;          // 0/64

    const int sw0 = ((quad)     ^ (l16 & 7)) << 3;
    const int sw1 = ((quad + 4) ^ (l16 & 7)) << 3;

    const int r8  = t >> 3;                    // 0..63
    const int qch = (t & 7) ^ (r8 & 7);
    const __hip_bfloat16* aS = A  + (size_t)(tileM + r8) * INNER_ + qch * 8;
    const __hip_bfloat16* bS = Bt + (size_t)(tileN + r8) * INNER_ + qch * 8;

    WSTG_A(WAB0, 0, 0); WSTG_A(WAB0, 1, 0); WSTG_A(WAB0, 2, 0); WSTG_A(WAB0, 3, 0);
    WSTG_B(WBB0, 0, 0); WSTG_B(WBB0, 1, 0);
    WSTG_B(WBB0 + 8192, 0, 1); WSTG_B(WBB0 + 8192, 1, 1);
    WVM2;
    BAR;

    f32x4_t acc[4][4];
#pragma unroll
    for (int i = 0; i < 4; i++)
#pragma unroll
        for (int j = 0; j < 4; j++) acc[i][j] = (f32x4_t){0.f, 0.f, 0.f, 0.f};
    bf16x8_t af[2][4], bfr[2][4];

    int rbm = 0;
    int sbm = 2;
#pragma unroll 1
    for (int it = 0; it < 32; ++it) {
        const int ra = (it & 1) ? WAB1 : WAB0;
        const int sa = (it & 1) ? WAB0 : WAB1;
        const int rb = WBB0 + rbm * 8192;
        const int sb = WBB0 + sbm * 8192;
        const bool stA = (it + 1 < 32);
        const bool stB = (it + 2 < 32);

        if (stA) { WSTG_A(sa, 0, it + 1); WSTG_A(sa, 1, it + 1);
                   WSTG_A(sa, 2, it + 1); WSTG_A(sa, 3, it + 1); }
        if (stB) { WSTG_B(sb, 0, it + 2); WSTG_B(sb, 1, it + 2); }

        WDSA(ra);
        WDSB(rb);
        WMM;

        if (stB) { WVM2; } else if (stA) { WVM0; }
        BAR;

        rbm = (rbm == 2) ? 0 : rbm + 1;
        sbm = (sbm == 2) ? 0 : sbm + 1;
    }

#pragma unroll
    for (int i = 0; i < 4; i++) {
        const int m = tileM + wm + i * 16 + quad * 4;
#pragma unroll
        for (int j = 0; j < 4; j++) {
            const int n = tileN + wn + j * 16 + l16;
            const float bn = bias[n];
#pragma unroll
            for (int r = 0; r < 4; r++)
                C[(size_t)(m + r) * D_ + n] = acc[i][j][r] + bn;
        }
    }
}

// ---------------------------------------------------------------- RMSNorm + RoPE
// Fused q+k per row: 512 threads, threads 0-255 -> q, 256-511 -> k.
__global__ __launch_bounds__(512)
void k_rmsrope2(__hip_bfloat16* __restrict__ qb, __hip_bfloat16* __restrict__ kb,
                const float* __restrict__ qn, const float* __restrict__ kn,
                const float* __restrict__ pcos, const float* __restrict__ psin,
                const float* __restrict__ lls, float qextra) {
    const int row  = blockIdx.x;
    const int l    = row & (L_ - 1);
    const int t    = threadIdx.x;
    const int half = t >> 8;                 // 0 = q, 1 = k
    const int tt   = t & 255;
    __hip_bfloat16* buf = half ? kb : qb;
    const float* w = half ? kn : qn;
    __hip_bfloat16* p = buf + (size_t)row * INNER_ + tt * 8;

    float x[8];
    {
        const unsigned short* ps = (const unsigned short*)p;
        ushort4 a = *(const ushort4*)ps;
        ushort4 b = *(const ushort4*)(ps + 4);
        unsigned short s[8] = {a.x, a.y, a.z, a.w, b.x, b.y, b.z, b.w};
#pragma unroll
        for (int i = 0; i < 8; i++) x[i] = bf2f(s[i]);
    }
    float ss = 0.f;
#pragma unroll
    for (int i = 0; i < 8; i++) ss += x[i] * x[i];
#pragma unroll
    for (int off = 32; off >= 1; off >>= 1) ss += __shfl_down(ss, off);
    __shared__ float red[8];
    if ((t & 63) == 0) red[t >> 6] = ss;
    __syncthreads();
    ss = half ? (red[4] + red[5]) + (red[6] + red[7])
              : (red[0] + red[1]) + (red[2] + red[3]);
    const float rstd = rsqrtf(ss * (1.0f / (float)INNER_) + 1e-6f);

    const float scale = half ? 1.0f : (qextra * lls[l]);

    const float4 c4 = ((const float4*)(pcos + (size_t)l * (INNER_ / 2)))[tt];
    const float4 s4 = ((const float4*)(psin + (size_t)l * (INNER_ / 2)))[tt];
    const float cc[4] = {c4.x, c4.y, c4.z, c4.w};
    const float sn[4] = {s4.x, s4.y, s4.z, s4.w};
    const float4 w0 = ((const float4*)w)[tt * 2];
    const float4 w1 = ((const float4*)w)[tt * 2 + 1];
    const float ww[8] = {w0.x, w0.y, w0.z, w0.w, w1.x, w1.y, w1.z, w1.w};

    union { __hip_bfloat16 h[8]; uint4 u; } pk;
#pragma unroll
    for (int pi = 0; pi < 4; pi++) {
        const float y1 = x[pi * 2]     * rstd * ww[pi * 2];
        const float y2 = x[pi * 2 + 1] * rstd * ww[pi * 2 + 1];
        pk.h[pi * 2]     = __float2bfloat16((y1 * cc[pi] - y2 * sn[pi]) * scale);
        pk.h[pi * 2 + 1] = __float2bfloat16((y1 * sn[pi] + y2 * cc[pi]) * scale);
    }
    *(uint4*)p = pk.u;
}

// ---------------------------------------------------------------- attention
// R6 version (best measured): QBLK=128, 8 waves, K/V double-buffered staging,
// raw barriers + counted vmcnt(4); q-tile pairing (p, 15-p).
__global__ __launch_bounds__(512)
void k_attn(const __hip_bfloat16* __restrict__ q,
            const __hip_bfloat16* __restrict__ k,
            const __hip_bfloat16* __restrict__ vT,
            __hip_bfloat16* __restrict__ o) {
    __shared__ __align__(16) __hip_bfloat16 Ks[2][64 * 128];   // [key][d] swizzled
    __shared__ __align__(16) __hip_bfloat16 Vs[2][128 * 64];   // [d][key] swizzled
    __shared__ __align__(16) __hip_bfloat16 Pt[8][16 * 72];    // [wave][qrow][key]

    const int p  = blockIdx.x;   // 0..7
    const int bh = blockIdx.y;
    const int b  = bh >> 4;
    const int h  = bh & 15;
    const int t = threadIdx.x, wave = t >> 6, lane = t & 63;
    const int quad = lane >> 4, l16 = lane & 15;

    const int kr = t >> 4;                          // 0..31
    const int kc = ((t & 15) ^ (kr & 15)) << 3;
    const int vr = t >> 3;                          // 0..63
    const int vc = ((t & 7) ^ (vr & 7)) << 3;
    const __hip_bfloat16* kbase = k  + (size_t)b * L_ * INNER_ + h * DH_;
    const __hip_bfloat16* vbase = vT + (size_t)bh * DH_ * L_;

#define STGKV(kt_, b_) do {                                                      \
    const int kv0_ = (kt_) * 64;                                                 \
    gld_lds16(kbase + (size_t)(kv0_ + kr)      * INNER_ + kc, &Ks[b_][t * 8]);   \
    gld_lds16(kbase + (size_t)(kv0_ + 32 + kr) * INNER_ + kc, &Ks[b_][4096 + t * 8]); \
    gld_lds16(vbase + (size_t)vr        * L_ + kv0_ + vc, &Vs[b_][t * 8]);       \
    gld_lds16(vbase + (size_t)(64 + vr) * L_ + kv0_ + vc, &Vs[b_][4096 + t * 8]);\
} while (0)

    for (int half = 0; half < 2; ++half) {
        const int qt = half ? (15 - p) : p;
        const int rowbase = qt * 128 + wave * 16;

        bf16x8_t aq[4];
        {
            const size_t qoff = (size_t)(b * L_ + rowbase + l16) * INNER_ + h * DH_;
#pragma unroll
            for (int kk = 0; kk < 4; kk++)
                aq[kk] = *(const bf16x8_t*)(q + qoff + kk * 32 + quad * 8);
        }

        f32x4_t oacc[8];
#pragma unroll
        for (int jj = 0; jj < 8; jj++) oacc[jj] = (f32x4_t){0.f, 0.f, 0.f, 0.f};
        float m_ = -1e30f, l_ = 0.f;

        const int nkt = 2 * qt + 2;
        STGKV(0, 0);                              // prologue
#pragma unroll 1
        for (int kt = 0; kt < nkt; ++kt) {
            const int kv0 = kt * 64;
            const int cur = kt & 1;
            const bool more = (kt + 1 < nkt);
            if (more) STGKV(kt + 1, cur ^ 1);     // prefetch next tile
            if (more) { WVM4; } else { WVM0; }    // current tile's 4 loads done
            BAR;

            if (kv0 <= rowbase + 15) {
                f32x4_t sacc[4];
#pragma unroll
                for (int tt = 0; tt < 4; tt++) sacc[tt] = (f32x4_t){0.f, 0.f, 0.f, 0.f};
#pragma unroll
                for (int kk = 0; kk < 4; kk++) {
                    bf16x8_t kf[4];
#pragma unroll
                    for (int tt = 0; tt < 4; tt++)
                        kf[tt] = *(const bf16x8_t*)&Ks[cur][(tt * 16 + l16) * 128 + (((kk * 4 + quad) ^ l16) << 3)];
#pragma unroll
                    for (int tt = 0; tt < 4; tt++)
                        sacc[tt] = __builtin_amdgcn_mfma_f32_16x16x32_bf16(
                            kf[tt], aq[kk], sacc[tt], 0, 0, 0);
                }

                if (kv0 + 63 > rowbase) {
                    const int qrow = rowbase + l16;
#pragma unroll
                    for (int tt = 0; tt < 4; tt++)
#pragma unroll
                        for (int r = 0; r < 4; r++)
                            if (kv0 + tt * 16 + quad * 4 + r > qrow) sacc[tt][r] = -1e30f;
                }

                float mx = sacc[0][0];
#pragma unroll
                for (int tt = 0; tt < 4; tt++)
#pragma unroll
                    for (int r = 0; r < 4; r++) mx = fmaxf(mx, sacc[tt][r]);
                mx = fmaxf(mx, __shfl_xor(mx, 16));
                mx = fmaxf(mx, __shfl_xor(mx, 32));
                const float mnew = fmaxf(m_, mx);
                const float alpha = exp2f(m_ - mnew);
                m_ = mnew;

                float ls = 0.f;
#pragma unroll
                for (int tt = 0; tt < 4; tt++) {
                    ushort4 pk;
                    float p0 = exp2f(sacc[tt][0] - mnew);
                    float p1 = exp2f(sacc[tt][1] - mnew);
                    float p2 = exp2f(sacc[tt][2] - mnew);
                    float p3 = exp2f(sacc[tt][3] - mnew);
                    ls += (p0 + p1) + (p2 + p3);
                    pk.x = f2bf(p0); pk.y = f2bf(p1); pk.z = f2bf(p2); pk.w = f2bf(p3);
                    *(ushort4*)&Pt[wave][l16 * 72 + tt * 16 + quad * 4] = pk;
                }
                ls += __shfl_xor(ls, 16);
                ls += __shfl_xor(ls, 32);
                l_ = l_ * alpha + ls;
#pragma unroll
                for (int jj = 0; jj < 8; jj++) {
                    oacc[jj][0] *= alpha; oacc[jj][1] *= alpha;
                    oacc[jj][2] *= alpha; oacc[jj][3] *= alpha;
                }

#pragma unroll
                for (int kk2 = 0; kk2 < 2; kk2++) {
                    bf16x8_t pf = *(const bf16x8_t*)&Pt[wave][l16 * 72 + kk2 * 32 + quad * 8];
#pragma unroll
                    for (int jj = 0; jj < 8; jj++) {
                        bf16x8_t vf = *(const bf16x8_t*)
                            &Vs[cur][(jj * 16 + l16) * 64 + (((kk2 * 4 + quad) ^ (l16 & 7)) << 3)];
                        oacc[jj] = __builtin_amdgcn_mfma_f32_16x16x32_bf16(vf, pf, oacc[jj], 0, 0, 0);
                    }
                }
            }
            BAR;
        }

        {
            const float inv = 1.0f / l_;
            __hip_bfloat16* orow = o + (size_t)(b * L_ + rowbase + l16) * INNER_ + h * DH_;
#pragma unroll
            for (int jj = 0; jj < 8; jj++) {
                ushort4 pk;
                pk.x = f2bf(oacc[jj][0] * inv);
                pk.y = f2bf(oacc[jj][1] * inv);
                pk.z = f2bf(oacc[jj][2] * inv);
                pk.w = f2bf(oacc[jj][3] * inv);
                *(ushort4*)(orow + jj * 16 + quad * 4) = pk;
            }
        }
    }
#undef STGKV
}

// ---------------------------------------------------------------- launch
extern "C" void kernel_launch(void* const* d_in, const int* in_sizes, int n_in,
                              void* d_out, int out_size, void* d_ws, size_t ws_size,
                              hipStream_t stream) {
    const float* x      = (const float*)d_in[0];
    const float* pe_cos = (const float*)d_in[1];
    const float* pe_sin = (const float*)d_in[2];
    const float* lls    = (const float*)d_in[3];
    const float* wq     = (const float*)d_in[4];
    const float* bq     = (const float*)d_in[5];
    const float* wk     = (const float*)d_in[6];
    const float* bk     = (const float*)d_in[7];
    const float* wv     = (const float*)d_in[8];
    const float* bv     = (const float*)d_in[9];
    const float* qn     = (const float*)d_in[10];
    const float* kn     = (const float*)d_in[11];
    const float* wo     = (const float*)d_in[12];
    const float* bo     = (const float*)d_in[13];

    char* ws = (char*)d_ws;
    const size_t SZ_W = (size_t)D_ * INNER_ * 2;   // 8 MB (bf16)
    const size_t SZ_M = (size_t)M_ * INNER_ * 2;   // 16 MB (bf16)
    __hip_bfloat16* xb     = (__hip_bfloat16*)ws;  ws += SZ_M;
    __hip_bfloat16* wqkvT  = (__hip_bfloat16*)ws;  ws += 3 * SZ_W;  // [6144][2048]
    __hip_bfloat16* woT    = (__hip_bfloat16*)ws;  ws += SZ_W;
    __hip_bfloat16* qb     = (__hip_bfloat16*)ws;  ws += SZ_M;
    __hip_bfloat16* kb     = (__hip_bfloat16*)ws;  ws += SZ_M;
    __hip_bfloat16* vT     = (__hip_bfloat16*)ws;  ws += SZ_M;
    __hip_bfloat16* ab     = (__hip_bfloat16*)ws;  ws += SZ_M;
    (void)in_sizes; (void)n_in; (void)out_size; (void)ws_size;

    // 0+1. fused: cast x (z=4) + all 4 weight transpose+casts (z=0..3)
    k_prep<<<dim3(64, 64, 5), dim3(256), 0, stream>>>(
        x, wq, wk, wv, wo,
        (unsigned short*)xb,
        (unsigned short*)wqkvT,
        (unsigned short*)(wqkvT + (size_t)INNER_ * D_),
        (unsigned short*)(wqkvT + 2 * (size_t)INNER_ * D_),
        (unsigned short*)woT);

    // 2. fused QKV projection (best verified variant)
    k_gemm_qkv<<<dim3(512), dim3(512), 0, stream>>>(xb, wqkvT, bq, bk, bv, qb, kb, vT);

    // 3. RMSNorm + RoPE, q+k fused per row
    const float qextra = 0.08838834764831843f /* rsqrt(128) */ * 1.4426950408889634f /* log2 e */;
    k_rmsrope2<<<dim3(M_), dim3(512), 0, stream>>>(qb, kb, qn, kn, pe_cos, pe_sin, lls, qextra);

    // 4. causal flash attention (R6 best: QBLK=128, dbuf K/V)
    k_attn<<<dim3(8, B_ * H_), dim3(512), 0, stream>>>(qb, kb, vT, ab);

    // 5. output projection -> d_out (f32)
    k_gemm_wo<<<dim3(256), dim3(512), 0, stream>>>(ab, woT, bo, (float*)d_out);
}